// Round 10
// baseline (189.361 us; speedup 1.0000x reference)
//
#include <hip/hip_runtime.h>

#define HASH_T    2097152u
#define HASH_MASK 2097151u
#define PRIME1 2654435761u
#define PRIME2 805459861u

typedef __attribute__((ext_vector_type(8))) short bf16x8;
typedef __attribute__((ext_vector_type(4))) float f32x4;
typedef __attribute__((ext_vector_type(4))) unsigned short us4;

#define LDS_STRIDE 328   // cols 0..63 feat/act0, 64..319 x->h2->h3, pad 8 (16B-aligned rows)

__device__ __forceinline__ unsigned short bf16_hi(float x){
    unsigned u = __float_as_uint(x);
    return (unsigned short)((u + 0x7FFFu + ((u >> 16) & 1u)) >> 16);
}
__device__ __forceinline__ float bf16f(unsigned short h){
    return __uint_as_float((unsigned)h << 16);
}
__device__ __forceinline__ void split2(float x, unsigned short& h, unsigned short& l){
    h = bf16_hi(x);
    l = bf16_hi(x - bf16f(h));
}

// ---------------- Kernel 0: pack weights into MFMA fragment order (bf16 hi/lo)
__global__ __launch_bounds__(256) void pack_weights_kernel(
    const float* __restrict__ Wd0, const float* __restrict__ Wd1,
    const float* __restrict__ Wv0, const float* __restrict__ Wv1,
    unsigned short* __restrict__ pk)
{
    int tid = blockIdx.x * 256 + threadIdx.x;
    if (tid >= 424 * 512) return;
    int pair = tid >> 9;
    int li   = tid & 511;
    int lane = li >> 3, j = li & 7;
    int kq = ((lane >> 4) << 3) + j;
    int cl = lane & 15;
    float w;
    if (pair < 8) {                       // Wd0 [40,64], K padded to 64
        int idx = pair; int kt = idx >> 2, ct = idx & 3;
        int k = kt * 32 + kq, c = ct * 16 + cl;
        w = (k < 40) ? Wd0[k * 64 + c] : 0.0f;
    } else if (pair < 40) {               // Wd1 [64,256]
        int idx = pair - 8; int kt = idx >> 4, ct = idx & 15;
        int k = kt * 32 + kq, c = ct * 16 + cl;
        w = Wd1[k * 256 + c];
    } else if (pair < 168) {              // Wv0 rows 0..255 (x part)
        int idx = pair - 40; int kt = idx >> 4, ct = idx & 15;
        int k = kt * 32 + kq, c = ct * 16 + cl;
        w = Wv0[k * 256 + c];
    } else {                              // Wv1: packed k 0..255 = ref rows 256..511 (x)
        int idx = pair - 168;             //      packed k 256..511 = ref rows 0..255 (h2)
        int kt = idx >> 4, ct = idx & 15;
        int k = kt * 32 + kq, c = ct * 16 + cl;
        int refr = (k < 256) ? (k + 256) : (k - 256);
        w = Wv1[refr * 256 + c];
    }
    unsigned short h, l; split2(w, h, l);
    pk[(size_t)pair * 1024 + li]       = h;
    pk[(size_t)pair * 1024 + 512 + li] = l;
}

// ---------------- fused kernel helpers (16-sample tile, st=1) ----------------
template<int KT, int NC>
__device__ __forceinline__ void gemm16(
    const unsigned short* __restrict__ pkBase, int NCT, int ct0, int kOff,
    const unsigned short (*Ahi)[LDS_STRIDE], const unsigned short (*Alo)[LDS_STRIDE],
    int lane, f32x4 acc[NC])
{
    const int r = lane & 15;
    const int kg = (lane >> 4) * 8;
    bf16x8 ah[NC], al[NC];
    #pragma unroll
    for (int ci = 0; ci < NC; ++ci) {
        const unsigned short* pf = pkBase + (size_t)(ct0 + ci) * 1024 + (size_t)lane * 8;
        ah[ci] = *reinterpret_cast<const bf16x8*>(pf);
        al[ci] = *reinterpret_cast<const bf16x8*>(pf + 512);
    }
    #pragma unroll
    for (int kt = 0; kt < KT; ++kt) {
        bf16x8 ahn[NC], aln[NC];
        if (kt + 1 < KT) {
            #pragma unroll
            for (int ci = 0; ci < NC; ++ci) {
                const unsigned short* pf = pkBase
                    + (size_t)((kt + 1) * NCT + ct0 + ci) * 1024 + (size_t)lane * 8;
                ahn[ci] = *reinterpret_cast<const bf16x8*>(pf);
                aln[ci] = *reinterpret_cast<const bf16x8*>(pf + 512);
            }
        }
        const int ke = kOff + kt * 32 + kg;
        bf16x8 bh = *reinterpret_cast<const bf16x8*>(&Ahi[r][ke]);
        bf16x8 bl = *reinterpret_cast<const bf16x8*>(&Alo[r][ke]);
        #pragma unroll
        for (int ci = 0; ci < NC; ++ci) {
            acc[ci] = __builtin_amdgcn_mfma_f32_16x16x32_bf16(ah[ci], bh, acc[ci], 0, 0, 0);
            acc[ci] = __builtin_amdgcn_mfma_f32_16x16x32_bf16(ah[ci], bl, acc[ci], 0, 0, 0);
            acc[ci] = __builtin_amdgcn_mfma_f32_16x16x32_bf16(al[ci], bh, acc[ci], 0, 0, 0);
        }
        if (kt + 1 < KT) {
            #pragma unroll
            for (int ci = 0; ci < NC; ++ci) { ah[ci] = ahn[ci]; al[ci] = aln[ci]; }
        }
    }
}

template<int NC, bool RELU>
__device__ __forceinline__ void epi16(
    f32x4 acc[NC], int ct0, int lane, const float* bias, int outOff,
    unsigned short (*Ahi)[LDS_STRIDE], unsigned short (*Alo)[LDS_STRIDE])
{
    const int r = lane & 15, g = lane >> 4;
    #pragma unroll
    for (int ci = 0; ci < NC; ++ci) {
        const int c0 = (ct0 + ci) * 16 + g * 4;
        const float4 bb = *reinterpret_cast<const float4*>(&bias[c0]);
        float v[4] = { acc[ci][0] + bb.x, acc[ci][1] + bb.y,
                       acc[ci][2] + bb.z, acc[ci][3] + bb.w };
        us4 H, L;
        #pragma unroll
        for (int q = 0; q < 4; ++q) {
            float vv = RELU ? fmaxf(v[q], 0.0f) : v[q];
            unsigned short h, l; split2(vv, h, l);
            H[q] = h; L[q] = l;
        }
        *reinterpret_cast<us4*>(&Ahi[r][outOff + c0]) = H;
        *reinterpret_cast<us4*>(&Alo[r][outOff + c0]) = L;
    }
}

// ---------------- Kernel 1: fused hash + MLP, 16 samples per block -----------
__global__ __launch_bounds__(256, 3) void zip_fused_kernel(
    const float* __restrict__ means, const float* __restrict__ stds,
    const float* __restrict__ vdirs, const float* __restrict__ emb,
    const unsigned short* __restrict__ pk,
    const float* __restrict__ bd0, const float* __restrict__ bd1,
    const float* __restrict__ Wv0, const float* __restrict__ bv0,
    const float* __restrict__ Wv1, const float* __restrict__ bv1,
    const float* __restrict__ Wr,  const float* __restrict__ br,
    float* __restrict__ outD, float* __restrict__ outRGB)
{
    __shared__ __align__(16) unsigned short sAhi[16][LDS_STRIDE];
    __shared__ __align__(16) unsigned short sAlo[16][LDS_STRIDE];
    __shared__ float sDe[32];
    __shared__ float sDv0[256];
    __shared__ float sDv1[256];

    const int t = threadIdx.x;
    const int lane = t & 63;
    const int w = t >> 6;
    const int b = blockIdx.x;          // 16-sample tile index
    const int ray = b >> 1;
    const int base = b * 16;

    // ---- phase 0: zero-pad feat cols 40..63 (16 rows); dir encoding
    if (t < 96) {
        int s = t / 6, j = t - s * 6;
        us4 z = {0, 0, 0, 0};
        *reinterpret_cast<us4*>(&sAhi[s][40 + j * 4]) = z;
        *reinterpret_cast<us4*>(&sAlo[s][40 + j * 4]) = z;
    }
    if (t < 27) {
        float d0 = vdirs[ray * 3 + 0], d1 = vdirs[ray * 3 + 1], d2 = vdirs[ray * 3 + 2];
        float val;
        if (t < 3) val = (t == 0) ? d0 : ((t == 1) ? d1 : d2);
        else {
            int u = t - 3, half = u / 12, jk = u % 12;
            int j = jk / 3, k = jk % 3;
            float dk = (k == 0) ? d0 : ((k == 1) ? d1 : d2);
            float xb = dk * (float)(1 << j);
            val = sinf(half ? (xb + 1.57079632679489662f) : xb);
        }
        sDe[t] = val;
    }
    __syncthreads();

    // ---- phase 1: hash gather; thread = (sample s = t>>4, u = t&15),
    //      u = corner c (u>>1) x n-half h (u&1); 3 multisamples per thread.
    {
        const int s = t >> 4, u = t & 15;
        const int c = u >> 1, h = u & 1;
        const int cxb = (c >> 2) & 1, cyb = (c >> 1) & 1, czb = c & 1;
        float mx[3], my[3], mz[3], s28[3];
        #pragma unroll
        for (int q = 0; q < 3; ++q) {
            int n = h * 3 + q;
            const float* mp = means + ((size_t)(base + s) * 6 + n) * 3;
            mx[q] = mp[0]; my[q] = mp[1]; mz[q] = mp[2];
            float sd = stds[(size_t)(base + s) * 6 + n];
            s28[q] = 8.0f * sd * sd;
        }
        const float inv6 = 1.0f / 6.0f;
        #pragma unroll 1
        for (int lp = 0; lp < 5; ++lp) {
            float4 ev[2][3];
            float cw[2][3];
            #pragma unroll
            for (int dl = 0; dl < 2; ++dl) {
                const int l = lp * 2 + dl;
                const float r = (float)(16 << l);
                const float* embL = emb + (size_t)l * HASH_T * 4u;
                #pragma unroll
                for (int q = 0; q < 3; ++q) {
                    float px = (mx[q] + 1.0f) * 0.5f * r - 0.5f;
                    float py = (my[q] + 1.0f) * 0.5f * r - 0.5f;
                    float pz = (mz[q] + 1.0f) * 0.5f * r - 0.5f;
                    float fx = floorf(px), fy = floorf(py), fz = floorf(pz);
                    float rx = px - fx, ry = py - fy, rz = pz - fz;
                    unsigned hx = (unsigned)((int)fx + cxb);
                    unsigned hy = (unsigned)((int)fy + cyb) * PRIME1;
                    unsigned hz = (unsigned)((int)fz + czb) * PRIME2;
                    unsigned idx = (hx ^ hy ^ hz) & HASH_MASK;
                    float wx = cxb ? rx : 1.0f - rx;
                    float wy = cyb ? ry : 1.0f - ry;
                    float wz = czb ? rz : 1.0f - rz;
                    float wl = erff(1.0f / fmaxf(sqrtf(s28[q] * r * r), 1e-10f));
                    cw[dl][q] = wx * wy * wz * wl;
                    ev[dl][q] = *reinterpret_cast<const float4*>(embL + (size_t)idx * 4u);
                }
            }
            #pragma unroll
            for (int dl = 0; dl < 2; ++dl) {
                float a0 = cw[dl][0]*ev[dl][0].x + cw[dl][1]*ev[dl][1].x + cw[dl][2]*ev[dl][2].x;
                float a1 = cw[dl][0]*ev[dl][0].y + cw[dl][1]*ev[dl][1].y + cw[dl][2]*ev[dl][2].y;
                float a2 = cw[dl][0]*ev[dl][0].z + cw[dl][1]*ev[dl][1].z + cw[dl][2]*ev[dl][2].z;
                float a3 = cw[dl][0]*ev[dl][0].w + cw[dl][1]*ev[dl][1].w + cw[dl][2]*ev[dl][2].w;
                #pragma unroll
                for (int m = 1; m < 16; m <<= 1) {
                    a0 += __shfl_xor(a0, m);
                    a1 += __shfl_xor(a1, m);
                    a2 += __shfl_xor(a2, m);
                    a3 += __shfl_xor(a3, m);
                }
                if (u == 0) {
                    const int l = lp * 2 + dl;
                    float o[4] = { a0 * inv6, a1 * inv6, a2 * inv6, a3 * inv6 };
                    us4 H, L;
                    #pragma unroll
                    for (int q = 0; q < 4; ++q) {
                        unsigned short hh, ll; split2(o[q], hh, ll);
                        H[q] = hh; L[q] = ll;
                    }
                    *reinterpret_cast<us4*>(&sAhi[s][l * 4]) = H;
                    *reinterpret_cast<us4*>(&sAlo[s][l * 4]) = L;
                }
            }
        }
    }
    __syncthreads();

    // ---- phase 2: per-ray dir-enc + bias tables (rank-27 correction)
    {
        int c = t;
        float a0 = bv0[c], a1 = bv1[c];
        #pragma unroll 3
        for (int k = 0; k < 27; ++k) {
            float dv = sDe[k];
            a0 += dv * Wv0[(256 + k) * 256 + c];
            a1 += dv * Wv1[(512 + k) * 256 + c];
        }
        sDv0[c] = a0; sDv1[c] = a1;
    }
    __syncthreads();

    // ---- phase 3 (L0): feat @ Wd0 -> act0 (cols 0..63), relu
    {
        f32x4 acc[1] = {};
        gemm16<2, 1>(pk, 4, w, 0, sAhi, sAlo, lane, acc);
        __syncthreads();                 // feat reads done before overwrite
        epi16<1, true>(acc, w, lane, bd0, 0, sAhi, sAlo);
    }
    __syncthreads();

    // ---- phase 4 (L1): act0 @ Wd1 -> x (cols 64..319); density from col 0
    {
        f32x4 acc[4] = {};
        gemm16<2, 4>(pk + 8192, 16, w * 4, 0, sAhi, sAlo, lane, acc);
        if (w == 0 && lane < 16) {
            float x0 = acc[0][0] + bd1[0];
            float vv = x0 - 1.0f;
            outD[base + lane] = fmaxf(vv, 0.0f) + log1pf(expf(-fabsf(vv)));
        }
        __syncthreads();                 // act0 reads done
        epi16<4, false>(acc, w * 4, lane, bd1, 64, sAhi, sAlo);
    }
    __syncthreads();

    // ---- phase 5: px = x @ Wv1[x-rows] (L3 partial, registers only)
    f32x4 px[4] = {};
    gemm16<8, 4>(pk + 172032, 16, w * 4, 64, sAhi, sAlo, lane, px);
    __syncthreads();

    // ---- phase 6 (L2): x @ Wv0 + sDv0 -> h2 (cols 64..319, overwrites x)
    {
        f32x4 acc[4] = {};
        gemm16<8, 4>(pk + 40960, 16, w * 4, 64, sAhi, sAlo, lane, acc);
        __syncthreads();                 // all x reads (phase5+6) done
        epi16<4, true>(acc, w * 4, lane, sDv0, 64, sAhi, sAlo);
    }
    __syncthreads();

    // ---- phase 7 (L3): px + h2 @ Wv1[h2-rows] + sDv1 -> h3 (cols 64..319)
    {
        gemm16<8, 4>(pk + 303104, 16, w * 4, 64, sAhi, sAlo, lane, px);
        __syncthreads();                 // h2 reads done before overwrite
        epi16<4, true>(px, w * 4, lane, sDv1, 64, sAhi, sAlo);
    }
    __syncthreads();

    // ---- phase 8 (L4): rgb = sigmoid(h3 @ Wr + br)*1.002 - 0.001
    if (t < 128) {
        int s = t >> 3, j = t & 7, k0 = 64 + j * 32;
        float p0 = 0.f, p1 = 0.f, p2 = 0.f;
        #pragma unroll 2
        for (int q = 0; q < 4; ++q) {
            us4 vh[2], vl[2];
            *reinterpret_cast<uint4*>(vh) = *reinterpret_cast<const uint4*>(&sAhi[s][k0 + q * 8]);
            *reinterpret_cast<uint4*>(vl) = *reinterpret_cast<const uint4*>(&sAlo[s][k0 + q * 8]);
            #pragma unroll
            for (int e = 0; e < 8; ++e) {
                int k = j * 32 + q * 8 + e;
                float hv = bf16f(((const unsigned short*)vh)[e]) + bf16f(((const unsigned short*)vl)[e]);
                p0 += hv * Wr[k * 3 + 0];
                p1 += hv * Wr[k * 3 + 1];
                p2 += hv * Wr[k * 3 + 2];
            }
        }
        #pragma unroll
        for (int m = 1; m < 8; m <<= 1) {
            p0 += __shfl_xor(p0, m);
            p1 += __shfl_xor(p1, m);
            p2 += __shfl_xor(p2, m);
        }
        if (j < 3) {
            float a = ((j == 0) ? p0 : (j == 1) ? p1 : p2) + br[j];
            float sg = 1.0f / (1.0f + expf(-a));
            outRGB[(size_t)(base + s) * 3 + j] = sg * 1.002f - 0.001f;
        }
    }
}

extern "C" void kernel_launch(void* const* d_in, const int* in_sizes, int n_in,
                              void* d_out, int out_size, void* d_ws, size_t ws_size,
                              hipStream_t stream) {
    const float* means = (const float*)d_in[1];
    const float* stds_ = (const float*)d_in[2];
    const float* vdirs = (const float*)d_in[3];
    const float* emb   = (const float*)d_in[4];
    const float* Wd0 = (const float*)d_in[5];
    const float* bd0 = (const float*)d_in[6];
    const float* Wd1 = (const float*)d_in[7];
    const float* bd1 = (const float*)d_in[8];
    const float* Wv0 = (const float*)d_in[9];
    const float* bv0 = (const float*)d_in[10];
    const float* Wv1 = (const float*)d_in[11];
    const float* bv1 = (const float*)d_in[12];
    const float* Wr  = (const float*)d_in[13];
    const float* br  = (const float*)d_in[14];

    const int B  = in_sizes[3] / 3;   // 1024 rays
    const int NS = B * 32;            // 32768 samples

    unsigned short* pk = (unsigned short*)d_ws;   // 424*1024 bf16 pairs = 868 KB

    hipLaunchKernelGGL(pack_weights_kernel, dim3((424 * 512 + 255) / 256), dim3(256), 0, stream,
                       Wd0, Wd1, Wv0, Wv1, pk);

    float* outD   = (float*)d_out;
    float* outRGB = outD + NS;
    hipLaunchKernelGGL(zip_fused_kernel, dim3(NS / 16), dim3(256), 0, stream,
                       means, stds_, vdirs, emb, pk,
                       bd0, bd1, Wv0, bv0, Wv1, bv1, Wr, br,
                       outD, outRGB);
}